// Round 3
// baseline (169.177 us; speedup 1.0000x reference)
//
#include <hip/hip_runtime.h>

#define S_LEN 2048
#define D_DIM 128
#define NBH   32
#define LOG2E 1.44269504f
#define NEGM  -1000000.0f

typedef __bf16 bf16x8 __attribute__((ext_vector_type(8)));
typedef short  s16x8  __attribute__((ext_vector_type(8)));
typedef float  f32x4  __attribute__((ext_vector_type(4)));
typedef float  f32x16 __attribute__((ext_vector_type(16)));
typedef unsigned int u32x4 __attribute__((ext_vector_type(4)));

typedef const __attribute__((address_space(1))) unsigned int glb_u32_t;
typedef __attribute__((address_space(3))) unsigned int lds_u32_t;

static __device__ __forceinline__ unsigned short f32_to_bf16_bits_exact(float f) {
    return (unsigned short)(__float_as_uint(f) >> 16);   // exact for small ints
}
static __device__ __forceinline__ float round_away(float t) {
    float r = floorf(fabsf(t) + 0.5f);
    return (t >= 0.0f) ? r : -r;
}
// p0,p1 -> one u32 of two bf16(floor(fma(p,127,0.5))) via v_perm
static __device__ __forceinline__ unsigned int pq_pack(float p0, float p1) {
    float a = floorf(fmaf(p0, 127.0f, 0.5f));
    float b = floorf(fmaf(p1, 127.0f, 0.5f));
    return __builtin_amdgcn_perm(__float_as_uint(b), __float_as_uint(a), 0x07060302);
}

// ---------------- per-token quantization of Q and K (float4/half-wave) -----
__global__ __launch_bounds__(256) void quant_qk_kernel(
    const float* __restrict__ q, const float* __restrict__ k,
    unsigned short* __restrict__ qq, unsigned short* __restrict__ kq,
    float* __restrict__ qs, float* __restrict__ ks)
{
    const int R = NBH * S_LEN;
    int w   = blockIdx.x * 8 + (threadIdx.x >> 5);
    int l32 = threadIdx.x & 31;
    const float* src; unsigned short* dq; float* ds; int row;
    if (w < R) { src = q; dq = qq; ds = qs; row = w; }
    else       { src = k; dq = kq; ds = ks; row = w - R; }
    size_t base = (size_t)row * D_DIM + l32 * 4;
    float4 x = *(const float4*)(src + base);
    float amax = fmaxf(fmaxf(fabsf(x.x), fabsf(x.y)), fmaxf(fabsf(x.z), fabsf(x.w)));
    #pragma unroll
    for (int m = 1; m < 32; m <<= 1) amax = fmaxf(amax, __shfl_xor(amax, m));
    float scale = fmaxf(amax, 1e-8f) / 127.0f;
    ushort4 o;
    o.x = f32_to_bf16_bits_exact(fminf(fmaxf(round_away(x.x / scale), -127.0f), 127.0f));
    o.y = f32_to_bf16_bits_exact(fminf(fmaxf(round_away(x.y / scale), -127.0f), 127.0f));
    o.z = f32_to_bf16_bits_exact(fminf(fmaxf(round_away(x.z / scale), -127.0f), 127.0f));
    o.w = f32_to_bf16_bits_exact(fminf(fmaxf(round_away(x.w / scale), -127.0f), 127.0f));
    *(ushort4*)(dq + base) = o;
    if (l32 == 0) ds[row] = scale;
}

// ---------------- per-head V amax (deterministic bit-pattern atomicMax) ----
__global__ __launch_bounds__(256) void vamax_kernel(const float* __restrict__ v,
                                                    unsigned int* __restrict__ vab)
{
    int bh = blockIdx.x >> 3, blk = blockIdx.x & 7;
    const float4* base = (const float4*)(v + (size_t)bh * S_LEN * D_DIM) + blk * 8192;
    int t = threadIdx.x;
    float am = 0.0f;
    #pragma unroll
    for (int i = 0; i < 32; ++i) {
        float4 x = base[t + i * 256];
        am = fmaxf(am, fmaxf(fmaxf(fabsf(x.x), fabsf(x.y)), fmaxf(fabsf(x.z), fabsf(x.w))));
    }
    #pragma unroll
    for (int m = 1; m < 64; m <<= 1) am = fmaxf(am, __shfl_xor(am, m));
    __shared__ float red[4];
    if ((t & 63) == 0) red[t >> 6] = am;
    __syncthreads();
    if (t == 0) {
        float a = fmaxf(fmaxf(red[0], red[1]), fmaxf(red[2], red[3]));
        atomicMax(&vab[bh], __float_as_uint(a));
    }
}

// ---------------- V quantize + transpose to [B,H,D,S] ----------------------
__global__ __launch_bounds__(256) void vtq_kernel(const float* __restrict__ v,
                                                  const unsigned int* __restrict__ vab,
                                                  unsigned short* __restrict__ vT)
{
    __shared__ unsigned short tileT[128][72];
    int bh = blockIdx.x >> 5, sb = blockIdx.x & 31;
    float scale = fmaxf(__uint_as_float(vab[bh]), 1e-8f) / 127.0f;
    int t = threadIdx.x;
    const float* src = v + ((size_t)bh * S_LEN + sb * 64) * D_DIM;
    #pragma unroll
    for (int it = 0; it < 8; ++it) {
        int c = t + it * 256;
        int rs = c >> 5, c4 = (c & 31) * 4;
        float4 x = *(const float4*)(src + rs * D_DIM + c4);
        float vals[4] = {x.x, x.y, x.z, x.w};
        #pragma unroll
        for (int u = 0; u < 4; ++u) {
            float r = fminf(fmaxf(round_away(vals[u] / scale), -127.0f), 127.0f);
            tileT[c4 + u][rs] = f32_to_bf16_bits_exact(r);
        }
    }
    __syncthreads();
    unsigned short* dst = vT + (size_t)bh * D_DIM * S_LEN + sb * 64;
    #pragma unroll
    for (int it = 0; it < 4; ++it) {
        int c = t + it * 256;
        int d = c >> 3, c8 = (c & 7) * 8;
        *(s16x8*)(dst + (size_t)d * S_LEN + c8) = *(const s16x8*)&tileT[d][c8];
    }
}

// ---------------- fused int8 flash attention (swapped 32x32, dbuf) ---------
__global__ __launch_bounds__(256) void attn_kernel(
    const unsigned short* __restrict__ qq,
    const unsigned short* __restrict__ kq,
    const unsigned short* __restrict__ vT,
    const float* __restrict__ qs,
    const float* __restrict__ ks,
    const unsigned int* __restrict__ vab,
    const float* __restrict__ smp,
    float* __restrict__ out)
{
    extern __shared__ char smem[];
    char*  KbA = smem;                     // 16 KB K tile (buf A), swizzled
    char*  KbB = smem + 16384;             // 16 KB K tile (buf B)
    char*  VbA = smem + 32768;             // 16 KB V^T tile (buf A), swizzled
    char*  VbB = smem + 49152;             // 16 KB V^T tile (buf B)
    float* ksl = (float*)(smem + 65536);   //  8 KB ks row of this head
    float* Ol  = (float*)smem;             // epilogue union: 2 x [32][132] f32

    const int tid  = threadIdx.x;
    const int lane = tid & 63;
    const int wid  = tid >> 6;
    const int c32  = lane & 31;
    const int hi   = lane >> 5;

    const int bid = blockIdx.x;
    const int g   = bid >> 5;
    const int qb  = (g < 8) ? (15 - g) : (g - 8);  // complementary pairing: CU load = const
    const int bh  = bid & 31;

    const float qk_scale = smp[0] * LOG2E;
    const float vscale   = fmaxf(__uint_as_float(vab[bh]), 1e-8f) / 127.0f;
    const float vs_term  = vscale / 127.0f;

    const int   q  = qb * 128 + c32 * 4 + wid;
    const float qf = qs[(size_t)bh * S_LEN + q] * qk_scale;

    // staging offsets (constant over j): linear LDS dest, pre-swizzled global src
    int kOff[4], vOff[4], lOff[4];
    #pragma unroll
    for (int it = 0; it < 4; ++it) {
        int L = (tid + it * 256) * 16;
        lOff[it] = L;
        int r = L >> 8, xk = L & 255;
        kOff[it] = r * 256 + (xk ^ ((r & 15) << 4));
        int rho = L >> 9, xv = L & 511;
        int c = xv ^ ((rho & 15) << 4);
        vOff[it] = ((c >> 7) * 32 + rho) * (S_LEN * 2) + (c & 127);
    }
    const char* kqb = (const char*)(kq + (size_t)bh * S_LEN * D_DIM);
    const char* vtb = (const char*)(vT + (size_t)bh * D_DIM * S_LEN);

    auto stage = [&](int jb, char* Kd, char* Vd) {
        #pragma unroll
        for (int it = 0; it < 4; ++it)
            __builtin_amdgcn_global_load_lds((glb_u32_t*)(kqb + jb * 256 + kOff[it]),
                                             (lds_u32_t*)(Kd + lOff[it]), 16, 0, 0);
        #pragma unroll
        for (int it = 0; it < 4; ++it)
            __builtin_amdgcn_global_load_lds((glb_u32_t*)(vtb + jb * 2 + vOff[it]),
                                             (lds_u32_t*)(Vd + lOff[it]), 16, 0, 0);
    };

    {   // stage full ks row (8 KB) once
        const f32x4* src = (const f32x4*)(ks + (size_t)bh * S_LEN);
        f32x4* dst = (f32x4*)ksl;
        dst[tid]       = src[tid];
        dst[tid + 256] = src[tid + 256];
    }

    bf16x8 qfrag[8];
    {
        const char* qrow = (const char*)(qq + ((size_t)bh * S_LEN + q) * D_DIM);
        #pragma unroll
        for (int st = 0; st < 8; ++st)
            qfrag[st] = __builtin_bit_cast(bf16x8, *(const s16x8*)(qrow + st * 32 + hi * 16));
    }

    float mrow = -__builtin_inff();
    float lrow = 0.0f;
    f32x16 oacc0, oacc1, oacc2, oacc3;
    #pragma unroll
    for (int i = 0; i < 16; ++i) { oacc0[i] = 0.f; oacc1[i] = 0.f; oacc2[i] = 0.f; oacc3[i] = 0.f; }

    stage(0, KbA, VbA);
    __syncthreads();

    const int jend = 2 * qb + 1;
    for (int j = 0; j <= jend; ++j) {
        const int jb = j * 64;
        const bool odd = j & 1;
        const char* Kc = odd ? KbB : KbA;
        const char* Vc = odd ? VbB : VbA;
        if (j < jend) stage(jb + 64, odd ? KbA : KbB, odd ? VbA : VbB);  // async prefetch

        // ---- swapped QK^T: S^T = K · Q^T ----
        f32x16 sc0, sc1;
        #pragma unroll
        for (int i = 0; i < 16; ++i) { sc0[i] = 0.f; sc1[i] = 0.f; }
        const int swz = (c32 & 15) << 4;
        #pragma unroll
        for (int st = 0; st < 8; ++st) {
            int cB = st * 32 + hi * 16;
            bf16x8 a0 = __builtin_bit_cast(bf16x8, *(const s16x8*)(Kc + c32 * 256        + (cB ^ swz)));
            bf16x8 a1 = __builtin_bit_cast(bf16x8, *(const s16x8*)(Kc + (c32 + 32) * 256 + (cB ^ swz)));
            sc0 = __builtin_amdgcn_mfma_f32_32x32x16_bf16(a0, qfrag[st], sc0, 0, 0, 0);
            sc1 = __builtin_amdgcn_mfma_f32_32x32x16_bf16(a1, qfrag[st], sc1, 0, 0, 0);
        }

        // ---- dequant + causal mask + row max ----
        const bool need_mask = (jb + 63 > qb * 128 + wid);
        float s0[16], s1[16];
        float mhA = -__builtin_inff(), mhB = -__builtin_inff();
        #pragma unroll
        for (int gg = 0; gg < 4; ++gg) {
            f32x4 kv0 = *(const f32x4*)&ksl[jb + gg * 8 + hi * 4];
            f32x4 kv1 = *(const f32x4*)&ksl[jb + 32 + gg * 8 + hi * 4];
            #pragma unroll
            for (int i = 0; i < 4; ++i) {
                int r = gg * 4 + i;
                float v0 = sc0[r] * qf * kv0[i];
                float v1 = sc1[r] * qf * kv1[i];
                if (need_mask) {
                    int key0 = jb + gg * 8 + i + hi * 4;
                    v0 = (q >= key0)      ? v0 : NEGM;
                    v1 = (q >= key0 + 32) ? v1 : NEGM;
                }
                s0[r] = v0; s1[r] = v1;
                if (i & 1) mhB = fmaxf(mhB, fmaxf(v0, v1));
                else       mhA = fmaxf(mhA, fmaxf(v0, v1));
            }
        }
        float mh   = fmaxf(mhA, mhB);
        float vmax = fmaxf(mh, __shfl_xor(mh, 32));

        const bool growAny = __any(vmax > mrow);   // wave-uniform
        float alpha = 1.0f;
        if (growAny) {
            float mnew = fmaxf(mrow, vmax);
            alpha = exp2f(mrow - mnew);
            mrow  = mnew;
        }

        // ---- p = exp2(s - m), tree-summed ----
        float tsum[16];
        #pragma unroll
        for (int r = 0; r < 16; ++r) {
            s0[r] = exp2f(s0[r] - mrow);
            s1[r] = exp2f(s1[r] - mrow);
            tsum[r] = s0[r] + s1[r];
        }
        #pragma unroll
        for (int stp = 8; stp >= 1; stp >>= 1)
            #pragma unroll
            for (int r = 0; r < stp; ++r) tsum[r] += tsum[r + stp];
        float psum = tsum[0] + __shfl_xor(tsum[0], 32);

        // ---- p_q -> packed bf16 words; cross-half exchange via permlane32_swap ----
        unsigned int W0[8], W1[8];
        #pragma unroll
        for (int gg = 0; gg < 4; ++gg) {
            W0[gg*2+0] = pq_pack(s0[gg*4+0], s0[gg*4+1]);
            W0[gg*2+1] = pq_pack(s0[gg*4+2], s0[gg*4+3]);
            W1[gg*2+0] = pq_pack(s1[gg*4+0], s1[gg*4+1]);
            W1[gg*2+1] = pq_pack(s1[gg*4+2], s1[gg*4+3]);
        }
        #pragma unroll
        for (int s = 0; s < 2; ++s) {
            asm("v_permlane32_swap_b32 %0, %1" : "+v"(W0[s*4+0]), "+v"(W0[s*4+2]));
            asm("v_permlane32_swap_b32 %0, %1" : "+v"(W0[s*4+1]), "+v"(W0[s*4+3]));
            asm("v_permlane32_swap_b32 %0, %1" : "+v"(W1[s*4+0]), "+v"(W1[s*4+2]));
            asm("v_permlane32_swap_b32 %0, %1" : "+v"(W1[s*4+1]), "+v"(W1[s*4+3]));
        }

        if (growAny) {   // exact skip when alpha==1 for all lanes
            oacc0 *= alpha; oacc1 *= alpha; oacc2 *= alpha; oacc3 *= alpha;
            lrow  *= alpha;
        }
        lrow += psum;

        // ---- PV: O^T += V^T · P^T ----
        #pragma unroll
        for (int t = 0; t < 2; ++t) {
            #pragma unroll
            for (int s = 0; s < 2; ++s) {
                const unsigned int* Wt = t ? W1 : W0;
                u32x4 uw; uw.x = Wt[s*4+0]; uw.y = Wt[s*4+1]; uw.z = Wt[s*4+2]; uw.w = Wt[s*4+3];
                bf16x8 bfrag = __builtin_bit_cast(bf16x8, uw);
                int cb = t * 64 + s * 32 + hi * 16;
                bf16x8 va;
                va = __builtin_bit_cast(bf16x8, *(const s16x8*)(Vc + c32 * 512 + ((cb +   0) ^ swz)));
                oacc0 = __builtin_amdgcn_mfma_f32_32x32x16_bf16(va, bfrag, oacc0, 0, 0, 0);
                va = __builtin_bit_cast(bf16x8, *(const s16x8*)(Vc + c32 * 512 + ((cb + 128) ^ swz)));
                oacc1 = __builtin_amdgcn_mfma_f32_32x32x16_bf16(va, bfrag, oacc1, 0, 0, 0);
                va = __builtin_bit_cast(bf16x8, *(const s16x8*)(Vc + c32 * 512 + ((cb + 256) ^ swz)));
                oacc2 = __builtin_amdgcn_mfma_f32_32x32x16_bf16(va, bfrag, oacc2, 0, 0, 0);
                va = __builtin_bit_cast(bf16x8, *(const s16x8*)(Vc + c32 * 512 + ((cb + 384) ^ swz)));
                oacc3 = __builtin_amdgcn_mfma_f32_32x32x16_bf16(va, bfrag, oacc3, 0, 0, 0);
            }
        }
        __syncthreads();   // drains prefetch (vmcnt) + guards buffer swap
    }

    // ---- epilogue: O^T -> LDS transpose -> coalesced stores ----
    const float inv = vs_term / lrow;
    for (int pass = 0; pass < 2; ++pass) {
        __syncthreads();
        if ((wid >> 1) == pass) {
            float* reg = Ol + (wid & 1) * 4224 + c32 * 132;
            #pragma unroll
            for (int r = 0; r < 16; ++r) {
                int drow = (r & 3) + 8 * (r >> 2) + 4 * hi;
                reg[drow]      = oacc0[r] * inv;
                reg[drow + 32] = oacc1[r] * inv;
                reg[drow + 64] = oacc2[r] * inv;
                reg[drow + 96] = oacc3[r] * inv;
            }
        }
        __syncthreads();
        #pragma unroll
        for (int it = 0; it < 8; ++it) {
            int idx = tid + it * 256;
            int w2  = idx >> 10;
            int rem = idx & 1023;
            int row = rem >> 5, c4 = rem & 31;
            f32x4 v4 = *(const f32x4*)(Ol + w2 * 4224 + row * 132 + c4 * 4);
            int qr = qb * 128 + row * 4 + pass * 2 + w2;
            *(f32x4*)(out + ((size_t)bh * S_LEN + qr) * D_DIM + c4 * 4) = v4;
        }
    }
}

extern "C" void kernel_launch(void* const* d_in, const int* in_sizes, int n_in,
                              void* d_out, int out_size, void* d_ws, size_t ws_size,
                              hipStream_t stream)
{
    const float* q  = (const float*)d_in[0];
    const float* k  = (const float*)d_in[1];
    const float* v  = (const float*)d_in[2];
    const float* sm = (const float*)d_in[3];

    if (ws_size < (size_t)50857000) return;
    char* ws = (char*)d_ws;
    unsigned short* qq = (unsigned short*)(ws);
    unsigned short* kq = (unsigned short*)(ws + (1u << 24));
    unsigned short* vT = (unsigned short*)(ws + (2u << 24));
    float*          qs = (float*)(ws + (3u << 24));
    float*          ks = (float*)(ws + (3u << 24) + 262144);
    unsigned int*  vab = (unsigned int*)(ws + (3u << 24) + 524288);
    float*         out = (float*)d_out;

    hipFuncSetAttribute((const void*)attn_kernel,
                        hipFuncAttributeMaxDynamicSharedMemorySize, 73728);

    hipMemsetAsync(vab, 0, NBH * sizeof(unsigned int), stream);
    quant_qk_kernel<<<dim3(16384), dim3(256), 0, stream>>>(q, k, qq, kq, qs, ks);
    vamax_kernel<<<dim3(256), dim3(256), 0, stream>>>(v, vab);
    vtq_kernel<<<dim3(1024), dim3(256), 0, stream>>>(v, vab, vT);
    attn_kernel<<<dim3(512), dim3(256), 73728, stream>>>(qq, kq, vT, qs, ks, vab, sm, out);
}